// Round 1
// baseline (534.227 us; speedup 1.0000x reference)
//
#include <hip/hip_runtime.h>
#include <hip/hip_bf16.h>

// FocalConstraintLoss: focal CE over [B,81,9] logits + sudoku row/col/box
// constraint smooth-L1. EPOCH=0 => dyn_w = 2.0*(0.5+0) = 1.0.
// total = ( sum_focal + (1/3)*sum_smoothl1 ) / (B*81)

constexpr int BLOCK = 256;
constexpr int WPB = 4;        // waves per block (wave = 64 lanes)
constexpr float ALPHA = 0.25f;

__global__ __launch_bounds__(BLOCK) void focal_constraint_main(
    const float* __restrict__ outs,   // [B,81,9]
    const int* __restrict__ tgts,     // [B,81]
    double* __restrict__ acc,         // [1] accumulator (pre-zeroed)
    int B)
{
    __shared__ float probs[WPB][736];   // 729 used per wave, padded
    __shared__ float red[WPB];

    const int lane = threadIdx.x & 63;
    const int wave = threadIdx.x >> 6;
    const int gw = blockIdx.x * WPB + wave;     // global wave id = sample walker
    const int nwaves = gridDim.x * WPB;

    float* P = probs[wave];
    float lacc = 0.0f;

    const int iters = (B + nwaves - 1) / nwaves;   // uniform across block
    for (int it = 0; it < iters; ++it) {
        const int s = gw + it * nwaves;
        const bool active = (s < B);

        // ---- phase 1: per-cell softmax + focal, write probs to LDS ----
        if (active) {
            const float* __restrict__ src = outs + (size_t)s * 729;
            const int* __restrict__ tg = tgts + (size_t)s * 81;
            #pragma unroll
            for (int cc = 0; cc < 2; ++cc) {
                const int cell = lane + cc * 64;
                if (cell < 81) {
                    float v[9];
                    #pragma unroll
                    for (int d = 0; d < 9; ++d) v[d] = src[cell * 9 + d];
                    float m = v[0];
                    #pragma unroll
                    for (int d = 1; d < 9; ++d) m = fmaxf(m, v[d]);
                    float e[9];
                    float sum = 0.0f;
                    #pragma unroll
                    for (int d = 0; d < 9; ++d) { e[d] = __expf(v[d] - m); sum += e[d]; }
                    const float inv = 1.0f / sum;
                    #pragma unroll
                    for (int d = 0; d < 9; ++d) P[cell * 9 + d] = e[d] * inv;
                    const int t = tg[cell];
                    const float ce = __logf(sum) - (v[t] - m);   // -logp[t]
                    const float pt = e[t] * inv;                  // exp(-ce)
                    const float om = 1.0f - pt;
                    lacc += ALPHA * om * om * ce;
                }
            }
        }
        __syncthreads();

        // ---- phase 2: 243 constraint sums (81 row + 81 col + 81 box) ----
        if (active) {
            #pragma unroll
            for (int k = 0; k < 4; ++k) {
                const int idx = lane + k * 64;
                if (idx < 243) {
                    const int grp = idx / 81;          // 0=row,1=col,2=box
                    const int t2 = idx - grp * 81;
                    const int a = t2 / 9;              // row / col / box id
                    const int d = t2 - a * 9;          // digit
                    float ssum = 0.0f;
                    if (grp == 0) {
                        #pragma unroll
                        for (int c = 0; c < 9; ++c) ssum += P[(a * 9 + c) * 9 + d];
                    } else if (grp == 1) {
                        #pragma unroll
                        for (int r = 0; r < 9; ++r) ssum += P[(r * 9 + a) * 9 + d];
                    } else {
                        const int br = (a / 3) * 3, bc = (a % 3) * 3;
                        #pragma unroll
                        for (int i = 0; i < 3; ++i)
                            #pragma unroll
                            for (int j = 0; j < 3; ++j)
                                ssum += P[((br + i) * 9 + (bc + j)) * 9 + d];
                    }
                    const float dd = ssum - 1.0f;
                    const float ad = fabsf(dd);
                    const float sl1 = (ad < 1.0f) ? 0.5f * dd * dd : ad - 0.5f;
                    lacc += sl1 * (1.0f / 3.0f);   // dyn_w=1.0 folded
                }
            }
        }
        __syncthreads();
    }

    // ---- reduce: wave shuffle -> block LDS -> one double atomic ----
    #pragma unroll
    for (int off = 32; off > 0; off >>= 1) lacc += __shfl_xor(lacc, off, 64);
    if (lane == 0) red[wave] = lacc;
    __syncthreads();
    if (threadIdx.x == 0) {
        double bsum = 0.0;
        #pragma unroll
        for (int w = 0; w < WPB; ++w) bsum += (double)red[w];
        atomicAdd(acc, bsum);
    }
}

__global__ void focal_constraint_finalize(const double* __restrict__ acc,
                                          float* __restrict__ out,
                                          double scale)
{
    out[0] = (float)(acc[0] * scale);
}

extern "C" void kernel_launch(void* const* d_in, const int* in_sizes, int n_in,
                              void* d_out, int out_size, void* d_ws, size_t ws_size,
                              hipStream_t stream) {
    const float* outs = (const float*)d_in[0];
    const int* tgts = (const int*)d_in[1];
    const int B = in_sizes[0] / 729;

    double* acc = (double*)d_ws;
    hipMemsetAsync(acc, 0, sizeof(double), stream);

    const int grid = 2048;
    focal_constraint_main<<<grid, BLOCK, 0, stream>>>(outs, tgts, acc, B);

    const double scale = 1.0 / ((double)B * 81.0);
    focal_constraint_finalize<<<1, 1, 0, stream>>>(acc, (float*)d_out, scale);
}

// Round 2
// 533.793 us; speedup vs baseline: 1.0008x; 1.0008x over previous
//
#include <hip/hip_runtime.h>
#include <hip/hip_bf16.h>

// FocalConstraintLoss: focal CE over [B,81,9] logits + sudoku row/col/box
// constraint smooth-L1. EPOCH=0 => dyn_w = 2.0*(0.5+0) = 1.0.
// total = ( sum_focal + (1/3)*sum_smoothl1 ) / (B*81)
//
// R2 structure: block stages 4 samples (2916 floats, 16B-aligned group) into
// LDS via coalesced float4 loads; each wave then owns one sample: softmax +
// focal from LDS logits (stride-9 dword reads = conflict-free), probs written
// back in place, then 243 constraint sums from LDS.

constexpr int BLOCK = 256;
constexpr int WPB = 4;        // waves per block = samples per block-iteration
constexpr float ALPHA = 0.25f;

__global__ __launch_bounds__(BLOCK) void focal_constraint_main(
    const float* __restrict__ outs,   // [B,81,9]
    const int* __restrict__ tgts,     // [B,81]
    double* __restrict__ acc,         // [1] accumulator (pre-zeroed)
    int ngroups)                      // B / 4
{
    __shared__ float P[WPB * 729];    // logits, overwritten by probs in place
    __shared__ int   T[WPB * 81];
    __shared__ float red[WPB];

    const int lane = threadIdx.x & 63;
    const int wave = threadIdx.x >> 6;

    float lacc = 0.0f;

    for (int g = blockIdx.x; g < ngroups; g += gridDim.x) {
        // ---- coalesced stage: 4 samples = 729 float4 logits + 81 int4 tgts ----
        const float4* __restrict__ src4 =
            reinterpret_cast<const float4*>(outs + (size_t)g * (WPB * 729));
        #pragma unroll
        for (int r = 0; r < 3; ++r) {
            const int idx = threadIdx.x + r * BLOCK;
            if (idx < 729) reinterpret_cast<float4*>(P)[idx] = src4[idx];
        }
        if (threadIdx.x < (WPB * 81) / 4) {
            reinterpret_cast<int4*>(T)[threadIdx.x] =
                reinterpret_cast<const int4*>(tgts + (size_t)g * (WPB * 81))[threadIdx.x];
        }
        __syncthreads();

        // ---- phase 1: per-cell softmax + focal; probs back to LDS in place ----
        float* __restrict__ Ps = P + wave * 729;
        const int* __restrict__ Ts = T + wave * 81;
        #pragma unroll
        for (int cc = 0; cc < 2; ++cc) {
            const int cell = lane + cc * 64;
            if (cell < 81) {
                float v[9];
                #pragma unroll
                for (int d = 0; d < 9; ++d) v[d] = Ps[cell * 9 + d];
                float m = v[0];
                #pragma unroll
                for (int d = 1; d < 9; ++d) m = fmaxf(m, v[d]);
                float e[9];
                float sum = 0.0f;
                #pragma unroll
                for (int d = 0; d < 9; ++d) { e[d] = __expf(v[d] - m); sum += e[d]; }
                const float inv = 1.0f / sum;
                #pragma unroll
                for (int d = 0; d < 9; ++d) Ps[cell * 9 + d] = e[d] * inv;
                const int t = Ts[cell];
                const float ce = __logf(sum) - (v[t] - m);   // -logp[t]
                const float pt = e[t] * inv;                  // exp(-ce)
                const float om = 1.0f - pt;
                lacc += ALPHA * om * om * ce;
            }
        }
        __syncthreads();

        // ---- phase 2: 243 constraint sums (81 row + 81 col + 81 box) ----
        #pragma unroll
        for (int k = 0; k < 4; ++k) {
            const int idx = lane + k * 64;
            if (idx < 243) {
                const int grp = idx / 81;          // 0=row,1=col,2=box
                const int t2 = idx - grp * 81;
                const int a = t2 / 9;              // row / col / box id
                const int d = t2 - a * 9;          // digit
                float ssum = 0.0f;
                if (grp == 0) {
                    #pragma unroll
                    for (int c = 0; c < 9; ++c) ssum += Ps[(a * 9 + c) * 9 + d];
                } else if (grp == 1) {
                    #pragma unroll
                    for (int r = 0; r < 9; ++r) ssum += Ps[(r * 9 + a) * 9 + d];
                } else {
                    const int br = (a / 3) * 3, bc = (a % 3) * 3;
                    #pragma unroll
                    for (int i = 0; i < 3; ++i)
                        #pragma unroll
                        for (int j = 0; j < 3; ++j)
                            ssum += Ps[((br + i) * 9 + (bc + j)) * 9 + d];
                }
                const float dd = ssum - 1.0f;
                const float ad = fabsf(dd);
                const float sl1 = (ad < 1.0f) ? 0.5f * dd * dd : ad - 0.5f;
                lacc += sl1 * (1.0f / 3.0f);   // dyn_w=1.0 folded
            }
        }
        __syncthreads();   // before next group's stage overwrites LDS
    }

    // ---- reduce: wave shuffle -> block LDS -> one double atomic ----
    #pragma unroll
    for (int off = 32; off > 0; off >>= 1) lacc += __shfl_xor(lacc, off, 64);
    if (lane == 0) red[wave] = lacc;
    __syncthreads();
    if (threadIdx.x == 0) {
        double bsum = 0.0;
        #pragma unroll
        for (int w = 0; w < WPB; ++w) bsum += (double)red[w];
        atomicAdd(acc, bsum);
    }
}

__global__ void focal_constraint_finalize(const double* __restrict__ acc,
                                          float* __restrict__ out,
                                          double scale)
{
    out[0] = (float)(acc[0] * scale);
}

extern "C" void kernel_launch(void* const* d_in, const int* in_sizes, int n_in,
                              void* d_out, int out_size, void* d_ws, size_t ws_size,
                              hipStream_t stream) {
    const float* outs = (const float*)d_in[0];
    const int* tgts = (const int*)d_in[1];
    const int B = in_sizes[0] / 729;
    const int ngroups = B / WPB;   // B = 131072 -> 32768 groups of 4 samples

    double* acc = (double*)d_ws;
    hipMemsetAsync(acc, 0, sizeof(double), stream);

    int grid = 2048;
    if (grid > ngroups) grid = ngroups;
    focal_constraint_main<<<grid, BLOCK, 0, stream>>>(outs, tgts, acc, ngroups);

    const double scale = 1.0 / ((double)B * 81.0);
    focal_constraint_finalize<<<1, 1, 0, stream>>>(acc, (float*)d_out, scale);
}

// Round 3
// 506.422 us; speedup vs baseline: 1.0549x; 1.0540x over previous
//
#include <hip/hip_runtime.h>
#include <hip/hip_bf16.h>

// FocalConstraintLoss: focal CE over [B,81,9] logits + sudoku row/col/box
// constraint smooth-L1. EPOCH=0 => dyn_w = 2.0*(0.5+0) = 1.0.
// total = ( sum_focal + (1/3)*sum_smoothl1 ) / (B*81)
//
// R3 structure: T14 async-stage split. Per block-iteration (group = 4
// samples): regs for NEXT group are loaded (nontemporal float4) while the
// CURRENT group is computed from LDS. Single LDS buffer, 2 barriers/group:
//   [barrier] ds_write regs -> LDS [barrier] issue next loads -> compute
// Per-block partial sums to d_ws slots (no memset, no global atomics),
// then a small finalize reduction kernel.

constexpr int BLOCK = 256;
constexpr int WPB = 4;        // waves per block = samples per group
constexpr float ALPHA = 0.25f;

typedef float v4f __attribute__((ext_vector_type(4)));
typedef int   v4i __attribute__((ext_vector_type(4)));

__global__ __launch_bounds__(BLOCK) void focal_constraint_main(
    const float* __restrict__ outs,   // [B,81,9]
    const int* __restrict__ tgts,     // [B,81]
    double* __restrict__ partials,    // [gridDim.x]
    int ngroups)                      // B / 4
{
    __shared__ float P[WPB * 729];    // logits, overwritten by probs in place
    __shared__ int   T[WPB * 81];
    __shared__ float red[WPB];

    const int tid = threadIdx.x;
    const int lane = tid & 63;
    const int wave = tid >> 6;

    float lacc = 0.0f;

    // ---- prologue: load first group into registers ----
    int g = blockIdx.x;
    v4f ra = {}, rb = {}, rc = {};
    v4i rt = {};
    {
        const v4f* __restrict__ s4 =
            reinterpret_cast<const v4f*>(outs + (size_t)g * (WPB * 729));
        ra = __builtin_nontemporal_load(&s4[tid]);
        rb = __builtin_nontemporal_load(&s4[tid + 256]);
        if (tid < 729 - 512) rc = __builtin_nontemporal_load(&s4[tid + 512]);
        const v4i* __restrict__ t4 =
            reinterpret_cast<const v4i*>(tgts + (size_t)g * (WPB * 81));
        if (tid < (WPB * 81) / 4) rt = __builtin_nontemporal_load(&t4[tid]);
    }

    for (; g < ngroups; g += gridDim.x) {
        // ---- write staged registers to LDS ----
        __syncthreads();   // previous group's compute done reading LDS
        {
            v4f* __restrict__ P4 = reinterpret_cast<v4f*>(P);
            P4[tid] = ra;
            P4[tid + 256] = rb;
            if (tid < 729 - 512) P4[tid + 512] = rc;
            if (tid < (WPB * 81) / 4) reinterpret_cast<v4i*>(T)[tid] = rt;
        }
        __syncthreads();

        // ---- issue NEXT group's loads (in flight during compute) ----
        const int gn = g + gridDim.x;
        if (gn < ngroups) {
            const v4f* __restrict__ s4 =
                reinterpret_cast<const v4f*>(outs + (size_t)gn * (WPB * 729));
            ra = __builtin_nontemporal_load(&s4[tid]);
            rb = __builtin_nontemporal_load(&s4[tid + 256]);
            if (tid < 729 - 512) rc = __builtin_nontemporal_load(&s4[tid + 512]);
            const v4i* __restrict__ t4 =
                reinterpret_cast<const v4i*>(tgts + (size_t)gn * (WPB * 81));
            if (tid < (WPB * 81) / 4) rt = __builtin_nontemporal_load(&t4[tid]);
        }

        // ---- phase 1: per-cell softmax + focal; probs back to LDS in place ----
        float* __restrict__ Ps = P + wave * 729;
        const int* __restrict__ Ts = T + wave * 81;
        #pragma unroll
        for (int cc = 0; cc < 2; ++cc) {
            const int cell = lane + cc * 64;
            if (cell < 81) {
                float v[9];
                #pragma unroll
                for (int d = 0; d < 9; ++d) v[d] = Ps[cell * 9 + d];
                float m = v[0];
                #pragma unroll
                for (int d = 1; d < 9; ++d) m = fmaxf(m, v[d]);
                float e[9];
                float sum = 0.0f;
                #pragma unroll
                for (int d = 0; d < 9; ++d) { e[d] = __expf(v[d] - m); sum += e[d]; }
                const float inv = 1.0f / sum;
                #pragma unroll
                for (int d = 0; d < 9; ++d) Ps[cell * 9 + d] = e[d] * inv;
                const int t = Ts[cell];
                const float ce = __logf(sum) - (v[t] - m);   // -logp[t]
                const float pt = e[t] * inv;                  // exp(-ce)
                const float om = 1.0f - pt;
                lacc += ALPHA * om * om * ce;
            }
        }
        __syncthreads();   // probs complete before phase 2 reads

        // ---- phase 2: 243 constraint sums (81 row + 81 col + 81 box) ----
        #pragma unroll
        for (int k = 0; k < 4; ++k) {
            const int idx = lane + k * 64;
            if (idx < 243) {
                const int grp = idx / 81;          // 0=row,1=col,2=box
                const int t2 = idx - grp * 81;
                const int a = t2 / 9;              // row / col / box id
                const int d = t2 - a * 9;          // digit
                float ssum = 0.0f;
                if (grp == 0) {
                    #pragma unroll
                    for (int c = 0; c < 9; ++c) ssum += Ps[(a * 9 + c) * 9 + d];
                } else if (grp == 1) {
                    #pragma unroll
                    for (int r = 0; r < 9; ++r) ssum += Ps[(r * 9 + a) * 9 + d];
                } else {
                    const int br = (a / 3) * 3, bc = (a % 3) * 3;
                    #pragma unroll
                    for (int i = 0; i < 3; ++i)
                        #pragma unroll
                        for (int j = 0; j < 3; ++j)
                            ssum += Ps[((br + i) * 9 + (bc + j)) * 9 + d];
                }
                const float dd = ssum - 1.0f;
                const float ad = fabsf(dd);
                const float sl1 = (ad < 1.0f) ? 0.5f * dd * dd : ad - 0.5f;
                lacc += sl1 * (1.0f / 3.0f);   // dyn_w=1.0 folded
            }
        }
        // loop-top barrier protects LDS before next ds_write
    }

    // ---- reduce: wave shuffle -> block LDS -> per-block partial slot ----
    #pragma unroll
    for (int off = 32; off > 0; off >>= 1) lacc += __shfl_xor(lacc, off, 64);
    if (lane == 0) red[wave] = lacc;
    __syncthreads();
    if (tid == 0) {
        double bsum = 0.0;
        #pragma unroll
        for (int w = 0; w < WPB; ++w) bsum += (double)red[w];
        partials[blockIdx.x] = bsum;   // unconditional: no memset needed
    }
}

__global__ __launch_bounds__(256) void focal_constraint_finalize(
    const double* __restrict__ partials,
    float* __restrict__ out,
    int n, double scale)
{
    __shared__ double sred[4];
    const int tid = threadIdx.x;
    double s = 0.0;
    for (int i = tid; i < n; i += 256) s += partials[i];
    #pragma unroll
    for (int off = 32; off > 0; off >>= 1) s += __shfl_xor(s, off, 64);
    if ((tid & 63) == 0) sred[tid >> 6] = s;
    __syncthreads();
    if (tid == 0) {
        out[0] = (float)((sred[0] + sred[1] + sred[2] + sred[3]) * scale);
    }
}

extern "C" void kernel_launch(void* const* d_in, const int* in_sizes, int n_in,
                              void* d_out, int out_size, void* d_ws, size_t ws_size,
                              hipStream_t stream) {
    const float* outs = (const float*)d_in[0];
    const int* tgts = (const int*)d_in[1];
    const int B = in_sizes[0] / 729;
    const int ngroups = B / WPB;   // B = 131072 -> 32768 groups of 4 samples

    double* partials = (double*)d_ws;

    int grid = 2048;
    if (grid > ngroups) grid = ngroups;
    focal_constraint_main<<<grid, BLOCK, 0, stream>>>(outs, tgts, partials, ngroups);

    const double scale = 1.0 / ((double)B * 81.0);
    focal_constraint_finalize<<<1, 256, 0, stream>>>(partials, (float*)d_out, grid, scale);
}